// Round 1
// baseline (642.950 us; speedup 1.0000x reference)
//
#include <hip/hip_runtime.h>

#define PLACEHOLDER (-1)

// Problem shape: B=256 seqs, K=8 drafts/seq, V=50257 vocab, T=B*K=2048 rows.
constexpr int MAXK = 16;        // compile-time unroll cap for K (runtime K=8)

// ---------------------------------------------------------------------------
// Kernel 1: one block of B threads. Computes starts (exclusive cumsum),
// accept run per sequence, writes all count outputs + out rows (except the
// recovered token slot), and hands kernel 2 the rejected-row index + slot.
// ---------------------------------------------------------------------------
__global__ __launch_bounds__(1024)
void k1_accept(const int* __restrict__ draft_token_ids,
               const int* __restrict__ num_draft_tokens,
               const float* __restrict__ draft_probs,
               const float* __restrict__ target_probs,
               const int* __restrict__ bonus_token_ids,
               const float* __restrict__ uniform_samples,
               int* __restrict__ out,              // B*(K+1)
               int* __restrict__ num_accepted,     // B
               int* __restrict__ accepted_counts,  // B
               int* __restrict__ recovered_counts, // B
               int* __restrict__ bonus_counts,     // B
               int* __restrict__ ws_info,          // B*2: {rej_row, slot or -1}
               int B, int K, int V, int T)
{
    __shared__ int s_scan[1024];
    const int b = threadIdx.x;
    const int n = (b < B) ? num_draft_tokens[b] : 0;
    s_scan[b] = n;
    __syncthreads();
    // Hillis-Steele inclusive scan over blockDim.x (== B)
    for (int off = 1; off < B; off <<= 1) {
        int v = 0;
        if (b >= off) v = s_scan[b - off];
        __syncthreads();
        s_scan[b] += v;
        __syncthreads();
    }
    if (b >= B) return;
    const int start = s_scan[b] - n;   // exclusive cumsum

    // Batch-issue independent loads: all dtoks first, then all probs/uniforms.
    int toks[MAXK];
    #pragma unroll
    for (int k = 0; k < MAXK; k++)
        if (k < K && k < n) toks[k] = draft_token_ids[start + k];

    float pd[MAXK], pt[MAXK], uu[MAXK];
    #pragma unroll
    for (int k = 0; k < MAXK; k++) {
        if (k < K && k < n) {
            const long long row = (long long)(start + k) * (long long)V;
            pd[k] = draft_probs[row + toks[k]];
            pt[k] = target_probs[row + toks[k]];
            uu[k] = uniform_samples[start + k];
        }
    }

    int num_acc = 0;
    bool running = true;
    #pragma unroll
    for (int k = 0; k < MAXK; k++) {
        if (k < K && k < n && running) {
            const float d  = fmaxf(pd[k], 1e-10f);
            const float ap = fminf(1.0f, pt[k] / d);
            if (uu[k] < ap) num_acc++; else running = false;
        }
    }
    const bool all_acc = (num_acc == n);

    int* orow = out + b * (K + 1);
    #pragma unroll
    for (int p = 0; p < MAXK + 1; p++) {
        if (p <= K) {
            int val = PLACEHOLDER;
            if (p < num_acc)        val = toks[p];
            else if (p == num_acc)  val = all_acc ? bonus_token_ids[b] : PLACEHOLDER;
            orow[p] = val;   // kernel 2 overwrites slot num_acc when !all_acc
        }
    }

    num_accepted[b]     = num_acc + 1;
    accepted_counts[b]  = num_acc;
    recovered_counts[b] = all_acc ? 0 : 1;
    bonus_counts[b]     = all_acc ? 1 : 0;

    int rej_pos = num_acc; if (rej_pos > K - 1) rej_pos = K - 1;
    int rej_row = start + rej_pos;
    if (rej_row > T - 1) rej_row = T - 1;
    if (rej_row < 0)     rej_row = 0;
    ws_info[2 * b]     = rej_row;
    ws_info[2 * b + 1] = all_acc ? -1 : num_acc;
}

// ---------------------------------------------------------------------------
// Kernel 2: one 1024-thread block per sequence. Pass A: tile sums of
// adjusted = max(t-d,0) (and of t, for the s<=1e-10 fallback) into LDS.
// Then locate the crossing tile via the 13 tile sums and rescan only that
// tile (intra-tile inclusive scan) to get the exact count.
// ---------------------------------------------------------------------------
#define K2_BLOCK 1024
#define K2_C     4
#define K2_TILE  (K2_BLOCK * K2_C)   // 4096
#define MAX_TILES 64

__global__ __launch_bounds__(K2_BLOCK)
void k2_resample(const float* __restrict__ draft_probs,
                 const float* __restrict__ target_probs,
                 const float* __restrict__ resample_uniforms,
                 const int* __restrict__ ws_info,
                 int* __restrict__ out,
                 int B, int K, int V)
{
    const int b    = blockIdx.x;
    const int slot = ws_info[2 * b + 1];
    if (slot < 0) return;                       // uniform across block
    const int row  = ws_info[2 * b];
    const float* __restrict__ trow = target_probs + (long long)row * (long long)V;
    const float* __restrict__ drow = draft_probs  + (long long)row * (long long)V;
    const float u = resample_uniforms[b];

    const int tid  = threadIdx.x;
    const int lane = tid & 63;
    const int wave = tid >> 6;                  // 0..15

    __shared__ float s_adj[MAX_TILES];
    __shared__ float s_t[MAX_TILES];
    __shared__ float s_wa[16];
    __shared__ float s_wt[16];
    __shared__ float s_w[16];
    __shared__ int   s_cnt[16];

    const int NT = (V + K2_TILE - 1) / K2_TILE; // 13 for V=50257

    // ---- Pass A: per-tile sums ----
    for (int t = 0; t < NT; t++) {
        const int base = t * K2_TILE;
        float ta[K2_C], da[K2_C];
        #pragma unroll
        for (int c = 0; c < K2_C; c++) {
            const int idx = base + c * K2_BLOCK + tid;
            const bool ok = idx < V;
            ta[c] = ok ? trow[idx] : 0.0f;
            da[c] = ok ? drow[idx] : 0.0f;
        }
        float aa = 0.0f, at = 0.0f;
        #pragma unroll
        for (int c = 0; c < K2_C; c++) {
            aa += fmaxf(ta[c] - da[c], 0.0f);
            at += ta[c];
        }
        #pragma unroll
        for (int off = 32; off; off >>= 1) {
            aa += __shfl_down(aa, off, 64);
            at += __shfl_down(at, off, 64);
        }
        if (lane == 0) { s_wa[wave] = aa; s_wt[wave] = at; }
        __syncthreads();
        if (tid == 0) {
            float sa = 0.0f, st = 0.0f;
            for (int w = 0; w < 16; w++) { sa += s_wa[w]; st += s_wt[w]; }
            s_adj[t] = sa; s_t[t] = st;
        }
        __syncthreads();
    }

    // ---- total + threshold + crossing tile (computed redundantly per thread) ----
    float s = 0.0f;
    for (int t = 0; t < NT; t++) s += s_adj[t];
    const bool  use_adj = (s > 1e-10f);
    const float thresh  = use_adj ? u * s : u;
    const float* sums   = use_adj ? s_adj : s_t;

    int tc = -1; float base = 0.0f;
    for (int t = 0; t < NT; t++) {
        const float ns = base + sums[t];
        if (ns >= thresh) { tc = t; break; }
        base = ns;
    }

    if (tc < 0) {                               // thresh beyond total: count=V
        if (tid == 0) out[b * (K + 1) + slot] = V - 1;
        return;
    }

    // ---- Pass B: rescan only the crossing tile ----
    int cnt = 0;
    float run = base;
    for (int c = 0; c < K2_C; c++) {
        const int idx = tc * K2_TILE + c * K2_BLOCK + tid;
        const bool ok = idx < V;
        float v = 0.0f;
        if (ok) {
            const float tv = trow[idx];
            v = use_adj ? fmaxf(tv - drow[idx], 0.0f) : tv;
        }
        // inclusive scan within wave
        float x = v;
        #pragma unroll
        for (int off = 1; off < 64; off <<= 1) {
            const float y = __shfl_up(x, off, 64);
            if (lane >= off) x += y;
        }
        if (lane == 63) s_w[wave] = x;
        __syncthreads();
        float wbase = 0.0f, chunk = 0.0f;
        for (int w = 0; w < 16; w++) {
            const float ws = s_w[w];
            if (w < wave) wbase += ws;
            chunk += ws;
        }
        const float incl = run + wbase + x;
        if (ok && incl < thresh) cnt++;
        run += chunk;
        __syncthreads();
    }
    #pragma unroll
    for (int off = 32; off; off >>= 1) cnt += __shfl_down(cnt, off, 64);
    if (lane == 0) s_cnt[wave] = cnt;
    __syncthreads();
    if (tid == 0) {
        int tot = 0;
        for (int w = 0; w < 16; w++) tot += s_cnt[w];
        int recovered = tc * K2_TILE + tot;
        if (recovered > V - 1) recovered = V - 1;
        out[b * (K + 1) + slot] = recovered;
    }
}

// ---------------------------------------------------------------------------
extern "C" void kernel_launch(void* const* d_in, const int* in_sizes, int n_in,
                              void* d_out, int out_size, void* d_ws, size_t ws_size,
                              hipStream_t stream)
{
    const int*   draft_token_ids   = (const int*)  d_in[0];
    const int*   num_draft_tokens  = (const int*)  d_in[1];
    const float* draft_probs       = (const float*)d_in[2];
    const float* target_probs      = (const float*)d_in[3];
    const int*   bonus_token_ids   = (const int*)  d_in[4];
    const float* uniform_samples   = (const float*)d_in[5];
    const float* resample_uniforms = (const float*)d_in[6];

    const int T = in_sizes[0];
    const int B = in_sizes[1];
    const int V = (int)((long long)in_sizes[2] / (long long)T);
    const int K = T / B;

    int* out              = (int*)d_out;
    int* num_accepted     = out + B * (K + 1);
    int* accepted_counts  = num_accepted + B;
    int* recovered_counts = accepted_counts + B;
    int* bonus_counts     = recovered_counts + B;
    int* ws_info          = (int*)d_ws;       // B*2 ints

    k1_accept<<<1, B, 0, stream>>>(draft_token_ids, num_draft_tokens,
                                   draft_probs, target_probs, bonus_token_ids,
                                   uniform_samples, out, num_accepted,
                                   accepted_counts, recovered_counts,
                                   bonus_counts, ws_info, B, K, V, T);

    k2_resample<<<B, K2_BLOCK, 0, stream>>>(draft_probs, target_probs,
                                            resample_uniforms, ws_info, out,
                                            B, K, V);
}